// Round 6
// baseline (530.870 us; speedup 1.0000x reference)
//
#include <hip/hip_runtime.h>
#include <hip/hip_bf16.h>
#include <hip/hip_fp8.h>
#include <math.h>

// Problem constants (fixed by setup_inputs): B=4096, D=512, V=50000.
#define B_ROWS 4096
#define DIMS   512
#define V_ROWS 50000
#define V_PAD  50048            // 391 * 128
#define NTILES 391              // V_PAD / 128
#define NT_PAD 392              // cands row stride (float4 units)
#define MTILES 32               // B_ROWS / 128
#define BKB    128              // K-bytes (fp8 elems) staged per iteration = one K=128 MFMA
#define EPSF   1e-8f
#define QSCALE 64.0f            // row pre-scale before fp8 quant (dodges e4m3 subnormals)
#define SCALE1 0x7F7F7F7F       // E8M0 unity scale broadcast to all 4 bytes

typedef float f32x4 __attribute__((ext_vector_type(4)));
typedef int   i32x4 __attribute__((ext_vector_type(4)));
typedef int   i32x8 __attribute__((ext_vector_type(8)));

// fp8 e4m3 (OCP) pack of 4 floats -> u32, bytes little-endian in k order
__device__ __forceinline__ unsigned int pk4_fp8(float a, float b, float c, float d) {
#if __has_builtin(__builtin_amdgcn_cvt_pk_fp8_f32)
  int w = __builtin_amdgcn_cvt_pk_fp8_f32(a, b, 0, false);   // bytes 0,1
  w = __builtin_amdgcn_cvt_pk_fp8_f32(c, d, w, true);        // bytes 2,3
  return (unsigned int)w;
#else
  __hip_fp8_e4m3 qa(a), qb(b), qc(c), qd(d);
  return (unsigned int)qa.__x | ((unsigned int)qb.__x << 8) |
         ((unsigned int)qc.__x << 16) | ((unsigned int)qd.__x << 24);
#endif
}

// async global->LDS, 16B per lane. LDS dest is wave-uniform base + lane*16.
__device__ __forceinline__ void lds_load16(const void* g, void* l) {
  __builtin_amdgcn_global_load_lds(
      (const __attribute__((address_space(1))) void*)g,
      (__attribute__((address_space(3))) void*)l, 16, 0, 0);
}

// merge two sorted (v0>=v1) top-2 pairs, no index tie-break
__device__ __forceinline__ void merge2(float& v0, int& i0, float& v1, int& i1,
                                       float ov0, int oi0, float ov1, int oi1) {
  bool bt = ov0 > v0;
  float lv = bt ? v0 : ov0; int li = bt ? i0 : oi0;
  float hv = bt ? ov1 : v1; int hi = bt ? oi1 : i1;
  if (bt) { v0 = ov0; i0 = oi0; }
  bool b2 = hv > lv;
  v1 = b2 ? hv : lv; i1 = b2 ? hi : li;
}

// value-strict, index tie-break (matches jax top_k first-occurrence semantics)
__device__ __forceinline__ bool better(float v, int i, float w, int j) {
  return (v > w) || (v == w && i < j);
}

__device__ __forceinline__ void merge2t(float& v0, int& i0, float& v1, int& i1,
                                        float ov0, int oi0, float ov1, int oi1) {
  bool bt = better(ov0, oi0, v0, i0);
  float lv = bt ? v0 : ov0; int li = bt ? i0 : oi0;
  float hv = bt ? ov1 : v1; int hi = bt ? oi1 : i1;
  if (bt) { v0 = ov0; i0 = oi0; }
  bool b2 = better(hv, hi, lv, li);
  v1 = b2 ? hv : lv; i1 = b2 ? hi : li;
}

// ---------------------------------------------------------------------------
// K1/K2: row-normalize fp32 -> fp8 e4m3 (scaled by QSCALE). One WAVE per row
// (64 lanes x 8 elems), grid-stride. Pad rows zero-filled. Also zeroes the
// scalar output (d_out poisoned before every call) from block 0 when out!=0.
// ---------------------------------------------------------------------------
__global__ __launch_bounds__(256)
void normalize_rows_kernel(const float* __restrict__ src, unsigned char* __restrict__ dst,
                           int nvalid, int ntotal, float* out_zero) {
  if (out_zero != nullptr && blockIdx.x == 0 && threadIdx.x == 0) *out_zero = 0.0f;
  const int l = threadIdx.x & 63;
  const int gw = (blockIdx.x * 256 + threadIdx.x) >> 6;
  const int nw = (gridDim.x * 256) >> 6;
  for (int row = gw; row < ntotal; row += nw) {
    if (row >= nvalid) {
      *(uint2*)&dst[(size_t)row * DIMS + l * 8] = make_uint2(0u, 0u);
      continue;
    }
    float4 v0 = ((const float4*)src)[(size_t)row * 128 + l * 2];
    float4 v1 = ((const float4*)src)[(size_t)row * 128 + l * 2 + 1];
    float ss = v0.x * v0.x + v0.y * v0.y + v0.z * v0.z + v0.w * v0.w
             + v1.x * v1.x + v1.y * v1.y + v1.z * v1.z + v1.w * v1.w;
    #pragma unroll
    for (int d = 1; d < 64; d <<= 1) ss += __shfl_xor(ss, d);
    float s = QSCALE / fmaxf(sqrtf(ss), EPSF);
    uint2 o;
    o.x = pk4_fp8(v0.x * s, v0.y * s, v0.z * s, v0.w * s);
    o.y = pk4_fp8(v1.x * s, v1.y * s, v1.z * s, v1.w * s);
    *(uint2*)&dst[(size_t)row * DIMS + l * 8] = o;
  }
}

// ---------------------------------------------------------------------------
// K3: MX-scaled fp8 MFMA GEMM (mfma_scale_f32_16x16x128_f8f6f4, unity E8M0
// scales). BKB=128 staged bytes = one K=128 MFMA per acc per k0 (4 k0 iters,
// 8 barriers total). XOR-8 swizzled LDS; fragment reads are 2x ds_read_b128
// per operand tile (quad lq covers k-bytes [32lq,+32) = global chunks 2lq,
// 2lq+1; slots s0=(2lq)^h, s1=s0^1).
// Round-5 established: this codegen has NO scratch spill at VGPR=96.
// Round-6 change: __launch_bounds__(256,4) -> 4 blocks/CU (was 2: the 2nd
// arg is waves/EU, and (256,2) self-capped occupancy to 8 waves/CU).
// LDS 36 KB x 4 = 147 KB <= 160 KB; VGPR cap 128 >= 96 observed.
// A/B use identical chunk->quad register order, so any HW-internal k
// permutation cancels in the dot product (round-4/5 verified, absmax 0).
// ---------------------------------------------------------------------------
__global__ __launch_bounds__(256, 4)
void gemm_top2_kernel(const unsigned char* __restrict__ A8,
                      const unsigned char* __restrict__ B8,
                      float4* __restrict__ cands) {
  __shared__ __align__(16) unsigned char As[128 * BKB];   // 16 KB
  __shared__ __align__(16) unsigned char Bs[128 * BKB];   // 16 KB
  __shared__ float4 wcand[128][2];                        //  4 KB

  const int bid = blockIdx.x;
  const int mt = bid & 31;        // 32 consecutive blocks share the B-tile
  const int nt = bid >> 5;        // 0..390
  const int m0 = mt * 128, n0 = nt * 128;

  const int tid = threadIdx.x;
  const int w = tid >> 6, l = tid & 63;
  const int wr = w >> 1, wc = w & 1;     // 2x2 wave grid, 64x64 per wave
  const int lq = l >> 4, lr = l & 15;
  const int h = lr & 7;                  // XOR swizzle key

  // fragment slot offsets (constant across k0)
  const int s0 = ((2 * lq) ^ h) * 16;    // byte offset of chunk 2lq
  const int s1 = ((2 * lq + 1) ^ h) * 16;

  f32x4 acc[4][4] = {};

  for (int k0 = 0; k0 < DIMS; k0 += BKB) {
    // stage A,B fp8 tiles: 1024 16B-chunks each (128 rows x 8 chunks)
    #pragma unroll
    for (int it = 0; it < 4; ++it) {
      const int chunk = it * 256 + w * 64 + l;   // 0..1023
      const int row = chunk >> 3, c = chunk & 7;
      const int gc = c ^ (row & 7);              // swizzled global chunk
      lds_load16(A8 + (size_t)(m0 + row) * DIMS + k0 + gc * 16,
                 &As[(it * 256 + w * 64) * 16]);
      lds_load16(B8 + (size_t)(n0 + row) * DIMS + k0 + gc * 16,
                 &Bs[(it * 256 + w * 64) * 16]);
    }
    __syncthreads();

    // B fragments for all 4 col-tiles (32 VGPRs live)
    i32x8 bf[4];
    #pragma unroll
    for (int tc = 0; tc < 4; ++tc) {
      const int rb = (wc * 64 + tc * 16 + lr) * BKB;
      i32x4 blo = *(const i32x4*)&Bs[rb + s0];
      i32x4 bhi = *(const i32x4*)&Bs[rb + s1];
      bf[tc] = __builtin_shufflevector(blo, bhi, 0, 1, 2, 3, 4, 5, 6, 7);
    }
    // A fragments one tile at a time; 4 MFMAs each
    #pragma unroll
    for (int tr = 0; tr < 4; ++tr) {
      const int ra = (wr * 64 + tr * 16 + lr) * BKB;
      i32x4 alo = *(const i32x4*)&As[ra + s0];
      i32x4 ahi = *(const i32x4*)&As[ra + s1];
      i32x8 af = __builtin_shufflevector(alo, ahi, 0, 1, 2, 3, 4, 5, 6, 7);
      #pragma unroll
      for (int tc = 0; tc < 4; ++tc)
        acc[tr][tc] = __builtin_amdgcn_mfma_scale_f32_16x16x128_f8f6f4(
            af, bf[tc], acc[tr][tc],
            0, 0,                 // cbsz = fp8(e4m3), blgp = fp8(e4m3)
            0, SCALE1,            // scale_a opsel, scale_a (unity all bytes)
            0, SCALE1);           // scale_b opsel, scale_b
    }
    __syncthreads();
  }

  // mask padded columns (only last N tile)
  const int colbase = n0 + wc * 64 + lr;
  #pragma unroll
  for (int tc = 0; tc < 4; ++tc) {
    if (colbase + tc * 16 >= V_ROWS) {
      #pragma unroll
      for (int tr = 0; tr < 4; ++tr)
        #pragma unroll
        for (int r = 0; r < 4; ++r)
          acc[tr][tc][r] = -1e30f;
    }
  }

  // per-row top-2 over this block's 128 cols.
  // C/D layout: row = (lane>>4)*4 + reg, col = lane&15 (per 16x16 tile).
  #pragma unroll
  for (int tr = 0; tr < 4; ++tr) {
    #pragma unroll
    for (int reg = 0; reg < 4; ++reg) {
      float v0 = -INFINITY, v1 = -INFINITY;
      int i0 = 0, i1 = 0;
      #pragma unroll
      for (int tc = 0; tc < 4; ++tc) {
        float v = acc[tr][tc][reg];
        int col = colbase + tc * 16;
        bool b0 = v > v0;
        bool b1 = v > v1;
        float sv1 = b0 ? v0 : (b1 ? v : v1);
        int   si1 = b0 ? i0 : (b1 ? col : i1);
        v0 = b0 ? v : v0;
        i0 = b0 ? col : i0;
        v1 = sv1; i1 = si1;
      }
      #pragma unroll
      for (int d = 1; d < 16; d <<= 1) {
        float ov0 = __shfl_xor(v0, d); int oi0 = __shfl_xor(i0, d);
        float ov1 = __shfl_xor(v1, d); int oi1 = __shfl_xor(i1, d);
        merge2(v0, i0, v1, i1, ov0, oi0, ov1, oi1);
      }
      if (lr == 0) {
        int rloc = wr * 64 + tr * 16 + lq * 4 + reg;
        wcand[rloc][wc] = make_float4(v0, __int_as_float(i0), v1, __int_as_float(i1));
      }
    }
  }
  __syncthreads();
  if (tid < 128) {
    float4 a = wcand[tid][0], b4 = wcand[tid][1];
    float v0 = a.x; int i0 = __float_as_int(a.y);
    float v1 = a.z; int i1 = __float_as_int(a.w);
    merge2(v0, i0, v1, i1, b4.x, __float_as_int(b4.y), b4.z, __float_as_int(b4.w));
    // transposed layout: [row][tile] so finalize reads are coalesced
    cands[(size_t)(m0 + tid) * NT_PAD + nt] =
        make_float4(v0, __int_as_float(i0), v1, __int_as_float(i1));
  }
}

// ---------------------------------------------------------------------------
// K5: per-row final. Merge 391 tile candidates -> global top-2 indices, then
// recompute d_pos / d_neg exactly in fp32 from the original inputs.
// ---------------------------------------------------------------------------
__global__ __launch_bounds__(256)
void finalize_kernel(const float* __restrict__ input, const float* __restrict__ target,
                     const float* __restrict__ veclist, const float4* __restrict__ cands,
                     float* __restrict__ out) {
  const int b = blockIdx.x;
  const int t = threadIdx.x;
  __shared__ float4 wpair[4];
  __shared__ int sidx[2];
  __shared__ float red[4][7];
  __shared__ int reda[4];

  // phase A: global top-2 across tiles (coalesced: cands[b][nt])
  float v0 = -INFINITY, v1 = -INFINITY;
  int i0 = 0x7FFFFFFF, i1 = 0x7FFFFFFF;
  for (int nt = t; nt < NTILES; nt += 256) {
    float4 c = cands[(size_t)b * NT_PAD + nt];
    float cv0 = c.x; int ci0 = __float_as_int(c.y);
    float cv1 = c.z; int ci1 = __float_as_int(c.w);
    if (better(cv0, ci0, v0, i0)) { v1 = v0; i1 = i0; v0 = cv0; i0 = ci0; }
    else if (better(cv0, ci0, v1, i1)) { v1 = cv0; i1 = ci0; }
    if (better(cv1, ci1, v0, i0)) { v1 = v0; i1 = i0; v0 = cv1; i0 = ci1; }
    else if (better(cv1, ci1, v1, i1)) { v1 = cv1; i1 = ci1; }
  }
  #pragma unroll
  for (int d = 1; d < 64; d <<= 1) {
    float ov0 = __shfl_xor(v0, d); int oi0 = __shfl_xor(i0, d);
    float ov1 = __shfl_xor(v1, d); int oi1 = __shfl_xor(i1, d);
    merge2t(v0, i0, v1, i1, ov0, oi0, ov1, oi1);
  }
  if ((t & 63) == 0) wpair[t >> 6] = make_float4(v0, __int_as_float(i0),
                                                 v1, __int_as_float(i1));
  __syncthreads();
  if (t == 0) {
    float4 p = wpair[0];
    float m0v = p.x; int m0i = __float_as_int(p.y);
    float m1v = p.z; int m1i = __float_as_int(p.w);
    for (int wd = 1; wd < 4; ++wd) {
      float4 q = wpair[wd];
      merge2t(m0v, m0i, m1v, m1i, q.x, __float_as_int(q.y),
              q.z, __float_as_int(q.w));
    }
    sidx[0] = m0i; sidx[1] = m1i;
  }
  __syncthreads();
  const int idx0 = sidx[0], idx1 = sidx[1];

  // phase B: exact fp32 dot products / norms
  const float2* xin = (const float2*)(input  + (size_t)b * DIMS);
  const float2* xtg = (const float2*)(target + (size_t)b * DIMS);
  const float2* xv0 = (const float2*)(veclist + (size_t)idx0 * DIMS);
  const float2* xv1 = (const float2*)(veclist + (size_t)idx1 * DIMS);
  float2 xi = xin[t], tg = xtg[t], a0 = xv0[t], a1 = xv1[t];
  float s[7];
  s[0] = xi.x * xi.x + xi.y * xi.y;
  s[1] = tg.x * tg.x + tg.y * tg.y;
  s[2] = xi.x * tg.x + xi.y * tg.y;
  s[3] = a0.x * a0.x + a0.y * a0.y;
  s[4] = xi.x * a0.x + xi.y * a0.y;
  s[5] = a1.x * a1.x + a1.y * a1.y;
  s[6] = xi.x * a1.x + xi.y * a1.y;
  bool eq = (a0.x == tg.x) && (a0.y == tg.y);
  int weq = __all(eq);
  #pragma unroll
  for (int k = 0; k < 7; ++k)
    #pragma unroll
    for (int d = 1; d < 64; d <<= 1) s[k] += __shfl_xor(s[k], d);
  if ((t & 63) == 0) {
    #pragma unroll
    for (int k = 0; k < 7; ++k) red[t >> 6][k] = s[k];
    reda[t >> 6] = weq;
  }
  __syncthreads();
  if (t == 0) {
    float r[7];
    #pragma unroll
    for (int k = 0; k < 7; ++k)
      r[k] = red[0][k] + red[1][k] + red[2][k] + red[3][k];
    bool eq0 = reda[0] && reda[1] && reda[2] && reda[3];
    float na  = fmaxf(sqrtf(r[0]), EPSF);
    float ntg = fmaxf(sqrtf(r[1]), EPSF);
    float simp = r[2] / (na * ntg);
    float d_pos = sqrtf(fmaxf(2.0f * (1.0f - simp), 1e-12f));
    float nn = eq0 ? fmaxf(sqrtf(r[5]), EPSF) : fmaxf(sqrtf(r[3]), EPSF);
    float dn = eq0 ? r[6] : r[4];
    float simn = dn / (na * nn);
    float d_neg = sqrtf(fmaxf(2.0f * (1.0f - simn), 1e-12f));
    float margin = 0.5f + d_pos - d_neg;          // GAMMA + d_pos - d_neg
    float contrib = 2.0f * fmaxf(margin, 0.0f) * (1.0f / (float)B_ROWS);  // RANK=2
    atomicAdd(out, contrib);
  }
}

// ---------------------------------------------------------------------------
// Workspace layout (bytes):
//   vnn  fp8 [50048][512]     @ 0          : 25,624,576
//   inn  fp8 [4096][512]      @ 25,624,576 :  2,097,152
//   cands float4 [4096][392]  @ 27,721,728 : 25,690,112   (total ~53.4 MB)
// ---------------------------------------------------------------------------
extern "C" void kernel_launch(void* const* d_in, const int* in_sizes, int n_in,
                              void* d_out, int out_size, void* d_ws, size_t ws_size,
                              hipStream_t stream) {
  const float* input   = (const float*)d_in[0];
  const float* target  = (const float*)d_in[1];
  const float* veclist = (const float*)d_in[2];
  float* out = (float*)d_out;
  char* ws = (char*)d_ws;
  unsigned char* vnn = (unsigned char*)ws;
  unsigned char* inn = (unsigned char*)(ws + 25624576);
  float4* cands = (float4*)(ws + 27721728);

  normalize_rows_kernel<<<2048, 256, 0, stream>>>(veclist, vnn, V_ROWS, V_PAD, out);
  normalize_rows_kernel<<<512, 256, 0, stream>>>(input, inn, B_ROWS, B_ROWS, nullptr);
  gemm_top2_kernel<<<MTILES * NTILES, 256, 0, stream>>>(inn, vnn, cands);
  finalize_kernel<<<B_ROWS, 256, 0, stream>>>(input, target, veclist, cands, out);
}

// Round 7
// 450.342 us; speedup vs baseline: 1.1788x; 1.1788x over previous
//
#include <hip/hip_runtime.h>
#include <hip/hip_bf16.h>
#include <hip/hip_fp8.h>
#include <math.h>

// Problem constants (fixed by setup_inputs): B=4096, D=512, V=50000.
#define B_ROWS 4096
#define DIMS   512
#define V_ROWS 50000
#define V_PAD  50048            // 391 * 128
#define NTILES 391              // V_PAD / 128
#define NT_PAD 392              // cands row stride (float4 units)
#define MTILES 32               // B_ROWS / 128
#define BKB    128              // K-bytes (fp8 elems) staged per iteration = one K=128 MFMA
#define EPSF   1e-8f
#define QSCALE 64.0f            // row pre-scale before fp8 quant (dodges e4m3 subnormals)
#define SCALE1 0x7F7F7F7F       // E8M0 unity scale broadcast to all 4 bytes

typedef float f32x4 __attribute__((ext_vector_type(4)));
typedef int   i32x4 __attribute__((ext_vector_type(4)));
typedef int   i32x8 __attribute__((ext_vector_type(8)));

// fp8 e4m3 (OCP) pack of 4 floats -> u32, bytes little-endian in k order
__device__ __forceinline__ unsigned int pk4_fp8(float a, float b, float c, float d) {
#if __has_builtin(__builtin_amdgcn_cvt_pk_fp8_f32)
  int w = __builtin_amdgcn_cvt_pk_fp8_f32(a, b, 0, false);   // bytes 0,1
  w = __builtin_amdgcn_cvt_pk_fp8_f32(c, d, w, true);        // bytes 2,3
  return (unsigned int)w;
#else
  __hip_fp8_e4m3 qa(a), qb(b), qc(c), qd(d);
  return (unsigned int)qa.__x | ((unsigned int)qb.__x << 8) |
         ((unsigned int)qc.__x << 16) | ((unsigned int)qd.__x << 24);
#endif
}

// async global->LDS, 16B per lane. LDS dest is wave-uniform base + lane*16.
__device__ __forceinline__ void lds_load16(const void* g, void* l) {
  __builtin_amdgcn_global_load_lds(
      (const __attribute__((address_space(1))) void*)g,
      (__attribute__((address_space(3))) void*)l, 16, 0, 0);
}

// merge two sorted (v0>=v1) top-2 pairs, no index tie-break
__device__ __forceinline__ void merge2(float& v0, int& i0, float& v1, int& i1,
                                       float ov0, int oi0, float ov1, int oi1) {
  bool bt = ov0 > v0;
  float lv = bt ? v0 : ov0; int li = bt ? i0 : oi0;
  float hv = bt ? ov1 : v1; int hi = bt ? oi1 : i1;
  if (bt) { v0 = ov0; i0 = oi0; }
  bool b2 = hv > lv;
  v1 = b2 ? hv : lv; i1 = b2 ? hi : li;
}

// value-strict, index tie-break (matches jax top_k first-occurrence semantics)
__device__ __forceinline__ bool better(float v, int i, float w, int j) {
  return (v > w) || (v == w && i < j);
}

__device__ __forceinline__ void merge2t(float& v0, int& i0, float& v1, int& i1,
                                        float ov0, int oi0, float ov1, int oi1) {
  bool bt = better(ov0, oi0, v0, i0);
  float lv = bt ? v0 : ov0; int li = bt ? i0 : oi0;
  float hv = bt ? ov1 : v1; int hi = bt ? oi1 : i1;
  if (bt) { v0 = ov0; i0 = oi0; }
  bool b2 = better(hv, hi, lv, li);
  v1 = b2 ? hv : lv; i1 = b2 ? hi : li;
}

// ---------------------------------------------------------------------------
// K1/K2: row-normalize fp32 -> fp8 e4m3 (scaled by QSCALE). One WAVE per row
// (64 lanes x 8 elems), grid-stride. Pad rows zero-filled.
// ---------------------------------------------------------------------------
__global__ __launch_bounds__(256)
void normalize_rows_kernel(const float* __restrict__ src, unsigned char* __restrict__ dst,
                           int nvalid, int ntotal) {
  const int l = threadIdx.x & 63;
  const int gw = (blockIdx.x * 256 + threadIdx.x) >> 6;
  const int nw = (gridDim.x * 256) >> 6;
  for (int row = gw; row < ntotal; row += nw) {
    if (row >= nvalid) {
      *(uint2*)&dst[(size_t)row * DIMS + l * 8] = make_uint2(0u, 0u);
      continue;
    }
    float4 v0 = ((const float4*)src)[(size_t)row * 128 + l * 2];
    float4 v1 = ((const float4*)src)[(size_t)row * 128 + l * 2 + 1];
    float ss = v0.x * v0.x + v0.y * v0.y + v0.z * v0.z + v0.w * v0.w
             + v1.x * v1.x + v1.y * v1.y + v1.z * v1.z + v1.w * v1.w;
    #pragma unroll
    for (int d = 1; d < 64; d <<= 1) ss += __shfl_xor(ss, d);
    float s = QSCALE / fmaxf(sqrtf(ss), EPSF);
    uint2 o;
    o.x = pk4_fp8(v0.x * s, v0.y * s, v0.z * s, v0.w * s);
    o.y = pk4_fp8(v1.x * s, v1.y * s, v1.z * s, v1.w * s);
    *(uint2*)&dst[(size_t)row * DIMS + l * 8] = o;
  }
}

// ---------------------------------------------------------------------------
// K3: MX-scaled fp8 MFMA GEMM (mfma_scale_f32_16x16x128_f8f6f4, unity E8M0
// scales). BKB=128 staged bytes = one K=128 MFMA per acc per k0 (4 k0 iters,
// 8 barriers total). XOR-8 swizzled LDS; fragment reads are 2x ds_read_b128
// per operand tile.
// Occupancy note (r5/r6 measured): this kernel needs ~96 VGPR + 64 AGPR acc
// = ~160 unified regs. (256,4) caps at 128 -> 526 MB scratch spill (r6);
// (256,2) wastes feasible waves (22.6% occ, r5). (256,3) caps at 170 ->
// fits, 3 blocks/CU (LDS 36KBx3=110KB, regs 160x12waves=1920<2048).
// A/B use identical chunk->quad register order, so any HW-internal k
// permutation cancels in the dot product (round-4/5 verified, absmax 0).
// ---------------------------------------------------------------------------
__global__ __launch_bounds__(256, 3)
void gemm_top2_kernel(const unsigned char* __restrict__ A8,
                      const unsigned char* __restrict__ B8,
                      float4* __restrict__ cands) {
  __shared__ __align__(16) unsigned char As[128 * BKB];   // 16 KB
  __shared__ __align__(16) unsigned char Bs[128 * BKB];   // 16 KB
  __shared__ float4 wcand[128][2];                        //  4 KB

  const int bid = blockIdx.x;
  const int mt = bid & 31;        // 32 consecutive blocks share the B-tile
  const int nt = bid >> 5;        // 0..390
  const int m0 = mt * 128, n0 = nt * 128;

  const int tid = threadIdx.x;
  const int w = tid >> 6, l = tid & 63;
  const int wr = w >> 1, wc = w & 1;     // 2x2 wave grid, 64x64 per wave
  const int lq = l >> 4, lr = l & 15;
  const int h = lr & 7;                  // XOR swizzle key

  // fragment slot offsets (constant across k0)
  const int s0 = ((2 * lq) ^ h) * 16;    // byte offset of chunk 2lq
  const int s1 = ((2 * lq + 1) ^ h) * 16;

  f32x4 acc[4][4] = {};

  for (int k0 = 0; k0 < DIMS; k0 += BKB) {
    // stage A,B fp8 tiles: 1024 16B-chunks each (128 rows x 8 chunks)
    #pragma unroll
    for (int it = 0; it < 4; ++it) {
      const int chunk = it * 256 + w * 64 + l;   // 0..1023
      const int row = chunk >> 3, c = chunk & 7;
      const int gc = c ^ (row & 7);              // swizzled global chunk
      lds_load16(A8 + (size_t)(m0 + row) * DIMS + k0 + gc * 16,
                 &As[(it * 256 + w * 64) * 16]);
      lds_load16(B8 + (size_t)(n0 + row) * DIMS + k0 + gc * 16,
                 &Bs[(it * 256 + w * 64) * 16]);
    }
    __syncthreads();

    // B fragments for all 4 col-tiles (32 VGPRs live)
    i32x8 bf[4];
    #pragma unroll
    for (int tc = 0; tc < 4; ++tc) {
      const int rb = (wc * 64 + tc * 16 + lr) * BKB;
      i32x4 blo = *(const i32x4*)&Bs[rb + s0];
      i32x4 bhi = *(const i32x4*)&Bs[rb + s1];
      bf[tc] = __builtin_shufflevector(blo, bhi, 0, 1, 2, 3, 4, 5, 6, 7);
    }
    // A fragments one tile at a time; 4 MFMAs each
    #pragma unroll
    for (int tr = 0; tr < 4; ++tr) {
      const int ra = (wr * 64 + tr * 16 + lr) * BKB;
      i32x4 alo = *(const i32x4*)&As[ra + s0];
      i32x4 ahi = *(const i32x4*)&As[ra + s1];
      i32x8 af = __builtin_shufflevector(alo, ahi, 0, 1, 2, 3, 4, 5, 6, 7);
      #pragma unroll
      for (int tc = 0; tc < 4; ++tc)
        acc[tr][tc] = __builtin_amdgcn_mfma_scale_f32_16x16x128_f8f6f4(
            af, bf[tc], acc[tr][tc],
            0, 0,                 // cbsz = fp8(e4m3), blgp = fp8(e4m3)
            0, SCALE1,            // scale_a opsel, scale_a (unity all bytes)
            0, SCALE1);           // scale_b opsel, scale_b
    }
    __syncthreads();
  }

  // mask padded columns (only last N tile)
  const int colbase = n0 + wc * 64 + lr;
  #pragma unroll
  for (int tc = 0; tc < 4; ++tc) {
    if (colbase + tc * 16 >= V_ROWS) {
      #pragma unroll
      for (int tr = 0; tr < 4; ++tr)
        #pragma unroll
        for (int r = 0; r < 4; ++r)
          acc[tr][tc][r] = -1e30f;
    }
  }

  // per-row top-2 over this block's 128 cols.
  // C/D layout: row = (lane>>4)*4 + reg, col = lane&15 (per 16x16 tile).
  #pragma unroll
  for (int tr = 0; tr < 4; ++tr) {
    #pragma unroll
    for (int reg = 0; reg < 4; ++reg) {
      float v0 = -INFINITY, v1 = -INFINITY;
      int i0 = 0, i1 = 0;
      #pragma unroll
      for (int tc = 0; tc < 4; ++tc) {
        float v = acc[tr][tc][reg];
        int col = colbase + tc * 16;
        bool b0 = v > v0;
        bool b1 = v > v1;
        float sv1 = b0 ? v0 : (b1 ? v : v1);
        int   si1 = b0 ? i0 : (b1 ? col : i1);
        v0 = b0 ? v : v0;
        i0 = b0 ? col : i0;
        v1 = sv1; i1 = si1;
      }
      #pragma unroll
      for (int d = 1; d < 16; d <<= 1) {
        float ov0 = __shfl_xor(v0, d); int oi0 = __shfl_xor(i0, d);
        float ov1 = __shfl_xor(v1, d); int oi1 = __shfl_xor(i1, d);
        merge2(v0, i0, v1, i1, ov0, oi0, ov1, oi1);
      }
      if (lr == 0) {
        int rloc = wr * 64 + tr * 16 + lq * 4 + reg;
        wcand[rloc][wc] = make_float4(v0, __int_as_float(i0), v1, __int_as_float(i1));
      }
    }
  }
  __syncthreads();
  if (tid < 128) {
    float4 a = wcand[tid][0], b4 = wcand[tid][1];
    float v0 = a.x; int i0 = __float_as_int(a.y);
    float v1 = a.z; int i1 = __float_as_int(a.w);
    merge2(v0, i0, v1, i1, b4.x, __float_as_int(b4.y), b4.z, __float_as_int(b4.w));
    // transposed layout: [row][tile] so finalize reads are coalesced
    cands[(size_t)(m0 + tid) * NT_PAD + nt] =
        make_float4(v0, __int_as_float(i0), v1, __int_as_float(i1));
  }
}

// ---------------------------------------------------------------------------
// K5: per-row final. Merge 391 tile candidates -> global top-2 indices, then
// recompute d_pos / d_neg exactly in fp32 from the original inputs.
// Writes per-row contribution to contrib[b] — NO single-address atomics
// (4096 device-scope atomicAdds to one address serialize across 8 XCDs;
// suspected source of the stubborn ~190 us non-GEMM residual).
// ---------------------------------------------------------------------------
__global__ __launch_bounds__(256)
void finalize_kernel(const float* __restrict__ input, const float* __restrict__ target,
                     const float* __restrict__ veclist, const float4* __restrict__ cands,
                     float* __restrict__ contrib) {
  const int b = blockIdx.x;
  const int t = threadIdx.x;
  __shared__ float4 wpair[4];
  __shared__ int sidx[2];
  __shared__ float red[4][7];
  __shared__ int reda[4];

  // phase A: global top-2 across tiles (coalesced: cands[b][nt])
  float v0 = -INFINITY, v1 = -INFINITY;
  int i0 = 0x7FFFFFFF, i1 = 0x7FFFFFFF;
  for (int nt = t; nt < NTILES; nt += 256) {
    float4 c = cands[(size_t)b * NT_PAD + nt];
    float cv0 = c.x; int ci0 = __float_as_int(c.y);
    float cv1 = c.z; int ci1 = __float_as_int(c.w);
    if (better(cv0, ci0, v0, i0)) { v1 = v0; i1 = i0; v0 = cv0; i0 = ci0; }
    else if (better(cv0, ci0, v1, i1)) { v1 = cv0; i1 = ci0; }
    if (better(cv1, ci1, v0, i0)) { v1 = v0; i1 = i0; v0 = cv1; i0 = ci1; }
    else if (better(cv1, ci1, v1, i1)) { v1 = cv1; i1 = ci1; }
  }
  #pragma unroll
  for (int d = 1; d < 64; d <<= 1) {
    float ov0 = __shfl_xor(v0, d); int oi0 = __shfl_xor(i0, d);
    float ov1 = __shfl_xor(v1, d); int oi1 = __shfl_xor(i1, d);
    merge2t(v0, i0, v1, i1, ov0, oi0, ov1, oi1);
  }
  if ((t & 63) == 0) wpair[t >> 6] = make_float4(v0, __int_as_float(i0),
                                                 v1, __int_as_float(i1));
  __syncthreads();
  if (t == 0) {
    float4 p = wpair[0];
    float m0v = p.x; int m0i = __float_as_int(p.y);
    float m1v = p.z; int m1i = __float_as_int(p.w);
    for (int wd = 1; wd < 4; ++wd) {
      float4 q = wpair[wd];
      merge2t(m0v, m0i, m1v, m1i, q.x, __float_as_int(q.y),
              q.z, __float_as_int(q.w));
    }
    sidx[0] = m0i; sidx[1] = m1i;
  }
  __syncthreads();
  const int idx0 = sidx[0], idx1 = sidx[1];

  // phase B: exact fp32 dot products / norms
  const float2* xin = (const float2*)(input  + (size_t)b * DIMS);
  const float2* xtg = (const float2*)(target + (size_t)b * DIMS);
  const float2* xv0 = (const float2*)(veclist + (size_t)idx0 * DIMS);
  const float2* xv1 = (const float2*)(veclist + (size_t)idx1 * DIMS);
  float2 xi = xin[t], tg = xtg[t], a0 = xv0[t], a1 = xv1[t];
  float s[7];
  s[0] = xi.x * xi.x + xi.y * xi.y;
  s[1] = tg.x * tg.x + tg.y * tg.y;
  s[2] = xi.x * tg.x + xi.y * tg.y;
  s[3] = a0.x * a0.x + a0.y * a0.y;
  s[4] = xi.x * a0.x + xi.y * a0.y;
  s[5] = a1.x * a1.x + a1.y * a1.y;
  s[6] = xi.x * a1.x + xi.y * a1.y;
  bool eq = (a0.x == tg.x) && (a0.y == tg.y);
  int weq = __all(eq);
  #pragma unroll
  for (int k = 0; k < 7; ++k)
    #pragma unroll
    for (int d = 1; d < 64; d <<= 1) s[k] += __shfl_xor(s[k], d);
  if ((t & 63) == 0) {
    #pragma unroll
    for (int k = 0; k < 7; ++k) red[t >> 6][k] = s[k];
    reda[t >> 6] = weq;
  }
  __syncthreads();
  if (t == 0) {
    float r[7];
    #pragma unroll
    for (int k = 0; k < 7; ++k)
      r[k] = red[0][k] + red[1][k] + red[2][k] + red[3][k];
    bool eq0 = reda[0] && reda[1] && reda[2] && reda[3];
    float na  = fmaxf(sqrtf(r[0]), EPSF);
    float ntg = fmaxf(sqrtf(r[1]), EPSF);
    float simp = r[2] / (na * ntg);
    float d_pos = sqrtf(fmaxf(2.0f * (1.0f - simp), 1e-12f));
    float nn = eq0 ? fmaxf(sqrtf(r[5]), EPSF) : fmaxf(sqrtf(r[3]), EPSF);
    float dn = eq0 ? r[6] : r[4];
    float simn = dn / (na * nn);
    float d_neg = sqrtf(fmaxf(2.0f * (1.0f - simn), 1e-12f));
    float margin = 0.5f + d_pos - d_neg;          // GAMMA + d_pos - d_neg
    contrib[b] = 2.0f * fmaxf(margin, 0.0f) * (1.0f / (float)B_ROWS);  // RANK=2
  }
}

// ---------------------------------------------------------------------------
// K6: sum 4096 per-row contributions -> out[0]. One block, no atomics.
// ---------------------------------------------------------------------------
__global__ __launch_bounds__(256)
void reduce_kernel(const float* __restrict__ contrib, float* __restrict__ out) {
  const int t = threadIdx.x;
  __shared__ float wsum[4];
  float s = 0.0f;
  for (int i = t; i < B_ROWS; i += 256) s += contrib[i];
  #pragma unroll
  for (int d = 1; d < 64; d <<= 1) s += __shfl_xor(s, d);
  if ((t & 63) == 0) wsum[t >> 6] = s;
  __syncthreads();
  if (t == 0) out[0] = wsum[0] + wsum[1] + wsum[2] + wsum[3];
}

// ---------------------------------------------------------------------------
// Workspace layout (bytes):
//   vnn  fp8 [50048][512]     @ 0          : 25,624,576
//   inn  fp8 [4096][512]      @ 25,624,576 :  2,097,152
//   cands float4 [4096][392]  @ 27,721,728 : 25,690,112
//   contrib float [4096]      @ 53,411,840 :     16,384   (total ~53.4 MB)
// ---------------------------------------------------------------------------
extern "C" void kernel_launch(void* const* d_in, const int* in_sizes, int n_in,
                              void* d_out, int out_size, void* d_ws, size_t ws_size,
                              hipStream_t stream) {
  const float* input   = (const float*)d_in[0];
  const float* target  = (const float*)d_in[1];
  const float* veclist = (const float*)d_in[2];
  float* out = (float*)d_out;
  char* ws = (char*)d_ws;
  unsigned char* vnn = (unsigned char*)ws;
  unsigned char* inn = (unsigned char*)(ws + 25624576);
  float4* cands = (float4*)(ws + 27721728);
  float* contrib = (float*)(ws + 53411840);

  normalize_rows_kernel<<<2048, 256, 0, stream>>>(veclist, vnn, V_ROWS, V_PAD);
  normalize_rows_kernel<<<512, 256, 0, stream>>>(input, inn, B_ROWS, B_ROWS);
  gemm_top2_kernel<<<MTILES * NTILES, 256, 0, stream>>>(inn, vnn, cands);
  finalize_kernel<<<B_ROWS, 256, 0, stream>>>(input, target, veclist, cands, contrib);
  reduce_kernel<<<1, 256, 0, stream>>>(contrib, out);
}